// Round 3
// baseline (278.740 us; speedup 1.0000x reference)
//
#include <hip/hip_runtime.h>

typedef unsigned short u16;
typedef unsigned int uint32;
typedef __bf16 bf16x8 __attribute__((ext_vector_type(8)));
typedef float f32x4 __attribute__((ext_vector_type(4)));

static constexpr int Gg = 64;
static constexpr int Nn = 2048;
static constexpr int Ee = 16384;
static constexpr int GN = Gg * Nn;   // 131072
static constexpr int GE = Gg * Ee;   // 1048576

__device__ __forceinline__ u16 f2u(float f) {  // round-to-nearest-even bf16
    uint32 i = __float_as_uint(f);
    uint32 r = (i + 0x7FFFu + ((i >> 16) & 1u)) >> 16;
    return (u16)r;
}
__device__ __forceinline__ float lo16f(uint32 v) { return __uint_as_float(v << 16); }
__device__ __forceinline__ float hi16f(uint32 v) { return __uint_as_float(v & 0xffff0000u); }

// ---------------- setup kernels ----------------

// per-graph LDS histogram of dst -> degc, dis, invdeg (no global atomics)
__global__ __launch_bounds__(1024) void k_hist(const int* __restrict__ ei, int* __restrict__ deg,
                                               float* __restrict__ dis, float* __restrict__ invdeg) {
    int g = blockIdx.x, t = threadIdx.x;
    __shared__ int h[2048];
    h[t] = 0; h[t + 1024] = 0;
    __syncthreads();
    #pragma unroll
    for (int k = 0; k < 16; ++k) {
        int d = ei[GE + g * Ee + k * 1024 + t];
        atomicAdd(&h[d & (Nn - 1)], 1);
    }
    __syncthreads();
    #pragma unroll
    for (int k = 0; k < 2; ++k) {
        int i = k * 1024 + t;
        int c = h[i];
        deg[(g << 11) + i] = c;
        float dd = 1.0f + (float)c;
        dis[(g << 11) + i] = rsqrtf(dd);
        invdeg[(g << 11) + i] = 1.0f / dd;
    }
}

// per-group (8 graphs) exclusive scan over nodes -> pos_pn[p][i] (absolute, base p<<17)
__global__ void k_scan_p(const int* __restrict__ deg, int* __restrict__ pos_pn) {
    int p = blockIdx.x, t = threadIdx.x;   // 1024 threads, 2 nodes each
    int i0 = 2 * t, i1 = 2 * t + 1;
    int c0 = 0, c1 = 0;
    #pragma unroll
    for (int g8 = 0; g8 < 8; ++g8) {
        int g = p * 8 + g8;
        c0 += deg[(g << 11) + i0];
        c1 += deg[(g << 11) + i1];
    }
    __shared__ int ps[1024];
    ps[t] = c0 + c1; __syncthreads();
    for (int off = 1; off < 1024; off <<= 1) {
        int v = (t >= off) ? ps[t - off] : 0;
        __syncthreads();
        ps[t] += v;
        __syncthreads();
    }
    int base = (p << 17) + ps[t] - (c0 + c1);
    pos_pn[p * 2049 + i0] = base;
    pos_pn[p * 2049 + i1] = base + c0;
    if (t == 1023) pos_pn[p * 2049 + 2048] = (p + 1) << 17;
}

// deterministic per-(g,i) starts within the (p,i) bucket
__global__ void k_start(const int* __restrict__ deg, const int* __restrict__ pos_pn,
                        int* __restrict__ gstart) {
    int i = blockIdx.x * 256 + threadIdx.x;   // node 0..2047
    #pragma unroll
    for (int p = 0; p < 8; ++p) {
        int run = pos_pn[p * 2049 + i];
        #pragma unroll
        for (int g8 = 0; g8 < 8; ++g8) {
            int g = p * 8 + g8;
            gstart[(g << 11) + i] = run;
            run += deg[(g << 11) + i];
        }
    }
}

// per-graph scatter with LDS cursors (no global atomics)
__global__ __launch_bounds__(1024) void k_scatter(const int* __restrict__ ei, const float* __restrict__ dis,
                                                  const int* __restrict__ gstart, int2* __restrict__ nme) {
    int g = blockIdx.x, t = threadIdx.x;
    __shared__ int curs[2048];
    curs[t] = gstart[(g << 11) + t];
    curs[t + 1024] = gstart[(g << 11) + t + 1024];
    __syncthreads();
    #pragma unroll
    for (int k = 0; k < 16; ++k) {
        int e = g * Ee + k * 1024 + t;
        int s = ei[e];          // src gid
        int d = ei[GE + e];     // dst gid
        int p = atomicAdd(&curs[d & (Nn - 1)], 1);
        nme[p] = make_int2(s, __float_as_int(dis[s] * dis[d]));
    }
}

// pack bottom half of Wm into MFMA B-fragment order:
// Wtp[((ks*8+ct)*64 + l)*8 + j] = bf16(Wm[(128 + ks*32+lq*8+j)*128 + ct*16+lm]), l=lq*16+lm
__global__ void k_trans(const float* __restrict__ Wm, u16* __restrict__ Wtp) {
    int tid = blockIdx.x * 256 + threadIdx.x;   // 16384
    int j = tid & 7, l = (tid >> 3) & 63, kc = tid >> 9;
    int ks = kc >> 3, ct = kc & 7, lm = l & 15, lq = l >> 4;
    int f = ks * 32 + lq * 8 + j, c = ct * 16 + lm;
    Wtp[tid] = f2u(Wm[(128 + f) * 128 + c]);
}

// A[g] = (ce @ Wm_top) + bm, ce = (x[center]*invdeg + incident edges) @ W1 + b1
__global__ void k_A(const float* __restrict__ x, const int* __restrict__ center,
                    const float* __restrict__ invdeg, const int* __restrict__ gstart,
                    const int* __restrict__ deg, const int2* __restrict__ nme,
                    const float* __restrict__ W1, const float* __restrict__ b1,
                    const float* __restrict__ Wm, const float* __restrict__ bm,
                    float* __restrict__ A) {
    int g = blockIdx.x, t = threadIdx.x;   // 128 threads
    __shared__ float cepre[128], ce[128];
    int cg = (g << 11) + center[g];
    float v = x[cg * 128 + t] * invdeg[cg];
    int p0 = gstart[cg], p1 = p0 + deg[cg];
    for (int e = p0; e < p1; ++e) {          // usually empty (center has no in-edges)
        int2 m = nme[e];
        v += __int_as_float(m.y) * x[m.x * 128 + t];
    }
    cepre[t] = v; __syncthreads();
    float a = b1[t];
    #pragma unroll 8
    for (int f = 0; f < 128; ++f) a += cepre[f] * W1[f * 128 + t];
    ce[t] = a; __syncthreads();
    float o = bm[t];
    #pragma unroll 8
    for (int h = 0; h < 128; ++h) o += ce[h] * Wm[h * 128 + t];
    A[g * 128 + t] = o;
}

// ---------------- mask + y GEMM (MFMA), packed xy ----------------
// xy row (256 u16): group k (u16[4k..4k+4)) = { y[2k], y[2k+1], x[2k], x[2k+1] } bf16
// B-frags from global Wtp (L1-resident).
// Epilogue: two-pass wave-internal LDS transpose (8 rows/pass). Each lane owns a
// contiguous 64B chunk of one xy row and emits it as FOUR BACK-TO-BACK 16B stores
// (q[0..3] held in registers) — previously the 4 stores were interleaved with
// global loads, leaving half-dirty L2 lines that were evicted and re-allocated:
// measured WRITE_SIZE 103MB vs 67MB ideal (+53%) and FETCH +19MB (write-allocate
// re-fetch). Completing each line within ~4 instructions removes both.
// No min-waves clamp: transient live set (q[4] + acc half) would force spills at
// the 8-wave/SIMD register budget, and occupancy was measured nearly irrelevant
// here (32%->62% bought 2%).
__global__ __launch_bounds__(256) void k_masky(const float* __restrict__ x,
                                               const u16* __restrict__ Wtp,
                                               const float* __restrict__ A,
                                               u16* __restrict__ xy) {
    __shared__ float sA[128];
    __shared__ float sC[4][8 * 132];
    int t = threadIdx.x;
    int tile = blockIdx.x;            // 0..2047, 64 rows each
    int g = tile >> 5;
    if (t < 128) sA[t] = A[g * 128 + t];
    __syncthreads();

    int w = t >> 6, l = t & 63;
    int lm = l & 15, lq = l >> 4;
    int row0 = tile * 64 + w * 16;
    const bf16x8* Bp = (const bf16x8*)Wtp;

    f32x4 acc[8] = {};
    #pragma unroll
    for (int ks = 0; ks < 4; ++ks) {
        const float* xp = x + (row0 + lm) * 128 + ks * 32 + lq * 8;
        float4 x0 = *(const float4*)(xp);
        float4 x1 = *(const float4*)(xp + 4);
        union { u16 u[8]; bf16x8 v; } af;
        af.u[0] = f2u(x0.x); af.u[1] = f2u(x0.y); af.u[2] = f2u(x0.z); af.u[3] = f2u(x0.w);
        af.u[4] = f2u(x1.x); af.u[5] = f2u(x1.y); af.u[6] = f2u(x1.z); af.u[7] = f2u(x1.w);
        #pragma unroll
        for (int ct = 0; ct < 8; ++ct) {
            bf16x8 b = Bp[(ks * 8 + ct) * 64 + l];
            acc[ct] = __builtin_amdgcn_mfma_f32_16x16x32_bf16(af.v, b, acc[ct], 0, 0, 0);
        }
    }

    // two-pass per-wave C transpose (wave-internal LDS round-trip, DS in-order per wave)
    float* myC = sC[w];
    int lr = l >> 3;            // LDS row slot 0..7
    int cc = (l & 7) * 16;      // 16 cols per lane
    #pragma unroll
    for (int hs = 0; hs < 2; ++hs) {
        #pragma unroll
        for (int ct = 0; ct < 8; ++ct) {
            myC[(lq * 2 + 0) * 132 + ct * 16 + lm] = acc[ct][hs * 2 + 0];
            myC[(lq * 2 + 1) * 132 + ct * 16 + lm] = acc[ct][hs * 2 + 1];
        }
        // slot lr holds C row (lr>>1)*4 + hs*2 + (lr&1)
        int grow = row0 + (lr >> 1) * 4 + hs * 2 + (lr & 1);
        const float* xr = x + grow * 128 + cc;
        u16* orow = xy + grow * 256;
        uint4 q0, q1, q2, q3;
        {
            float4 ca = *(const float4*)(myC + lr * 132 + cc);
            float4 cb = *(const float4*)(myC + lr * 132 + cc + 4);
            float4 xa = *(const float4*)(xr);
            float4 xd = *(const float4*)(xr + 4);
            float m0 = fmaxf(ca.x + sA[cc + 0], 0.f) * xa.x;
            float m1 = fmaxf(ca.y + sA[cc + 1], 0.f) * xa.y;
            float m2 = fmaxf(ca.z + sA[cc + 2], 0.f) * xa.z;
            float m3 = fmaxf(ca.w + sA[cc + 3], 0.f) * xa.w;
            float m4 = fmaxf(cb.x + sA[cc + 4], 0.f) * xd.x;
            float m5 = fmaxf(cb.y + sA[cc + 5], 0.f) * xd.y;
            float m6 = fmaxf(cb.z + sA[cc + 6], 0.f) * xd.z;
            float m7 = fmaxf(cb.w + sA[cc + 7], 0.f) * xd.w;
            q0.x = (uint32)f2u(m0) | ((uint32)f2u(m1) << 16);
            q0.y = (uint32)f2u(xa.x) | ((uint32)f2u(xa.y) << 16);
            q0.z = (uint32)f2u(m2) | ((uint32)f2u(m3) << 16);
            q0.w = (uint32)f2u(xa.z) | ((uint32)f2u(xa.w) << 16);
            q1.x = (uint32)f2u(m4) | ((uint32)f2u(m5) << 16);
            q1.y = (uint32)f2u(xd.x) | ((uint32)f2u(xd.y) << 16);
            q1.z = (uint32)f2u(m6) | ((uint32)f2u(m7) << 16);
            q1.w = (uint32)f2u(xd.z) | ((uint32)f2u(xd.w) << 16);
        }
        {
            float4 ca = *(const float4*)(myC + lr * 132 + cc + 8);
            float4 cb = *(const float4*)(myC + lr * 132 + cc + 12);
            float4 xa = *(const float4*)(xr + 8);
            float4 xd = *(const float4*)(xr + 12);
            float m0 = fmaxf(ca.x + sA[cc + 8], 0.f) * xa.x;
            float m1 = fmaxf(ca.y + sA[cc + 9], 0.f) * xa.y;
            float m2 = fmaxf(ca.z + sA[cc + 10], 0.f) * xa.z;
            float m3 = fmaxf(ca.w + sA[cc + 11], 0.f) * xa.w;
            float m4 = fmaxf(cb.x + sA[cc + 12], 0.f) * xd.x;
            float m5 = fmaxf(cb.y + sA[cc + 13], 0.f) * xd.y;
            float m6 = fmaxf(cb.z + sA[cc + 14], 0.f) * xd.z;
            float m7 = fmaxf(cb.w + sA[cc + 15], 0.f) * xd.w;
            q2.x = (uint32)f2u(m0) | ((uint32)f2u(m1) << 16);
            q2.y = (uint32)f2u(xa.x) | ((uint32)f2u(xa.y) << 16);
            q2.z = (uint32)f2u(m2) | ((uint32)f2u(m3) << 16);
            q2.w = (uint32)f2u(xa.z) | ((uint32)f2u(xa.w) << 16);
            q3.x = (uint32)f2u(m4) | ((uint32)f2u(m5) << 16);
            q3.y = (uint32)f2u(xd.x) | ((uint32)f2u(xd.y) << 16);
            q3.z = (uint32)f2u(m6) | ((uint32)f2u(m7) << 16);
            q3.w = (uint32)f2u(xd.z) | ((uint32)f2u(xd.w) << 16);
        }
        // full 64B per lane, 4 consecutive 16B stores — line completes immediately
        *(uint4*)(orow + 2 * cc) = q0;
        *(uint4*)(orow + 2 * cc + 8) = q1;
        *(uint4*)(orow + 2 * cc + 16) = q2;
        *(uint4*)(orow + 2 * cc + 24) = q3;
    }
}

// ---------------- propagation: half-wave row mapping, 2 rows per load ----------------
#define ACC8(v, cf)                                                     \
    aY0 += (cf) * lo16f((v).x); aY1 += (cf) * hi16f((v).x);             \
    aX0 += (cf) * lo16f((v).y); aX1 += (cf) * hi16f((v).y);             \
    aY2 += (cf) * lo16f((v).z); aY3 += (cf) * hi16f((v).z);             \
    aX2 += (cf) * lo16f((v).w); aX3 += (cf) * hi16f((v).w);

__global__ __launch_bounds__(256) void k_propx(const u16* __restrict__ xy,
                                               const float* __restrict__ invdeg,
                                               const int* __restrict__ pos_pn,
                                               const int2* __restrict__ nme,
                                               float* __restrict__ zp) {
    int b = blockIdx.x;
    int p = b & 7, c = b >> 3;
    int t = threadIdx.x, w = t >> 6, l = t & 63;
    int half = l >> 5, cl = l & 31;
    int i = c * 4 + w;
    float aY0 = 0.f, aY1 = 0.f, aY2 = 0.f, aY3 = 0.f;
    float aX0 = 0.f, aX1 = 0.f, aX2 = 0.f, aX3 = 0.f;

    #pragma unroll
    for (int k = 0; k < 4; ++k) {
        int gid = ((p * 8 + 2 * k + half) << 11) + i;
        float cf = invdeg[gid];
        uint4 v = *(const uint4*)(xy + gid * 256 + cl * 8);
        ACC8(v, cf)
    }

    int j = pos_pn[p * 2049 + i], jend = pos_pn[p * 2049 + i + 1];
    for (; j + 7 < jend; j += 8) {
        int2 m0 = nme[j + half];
        int2 m1 = nme[j + 2 + half];
        int2 m2 = nme[j + 4 + half];
        int2 m3 = nme[j + 6 + half];
        uint4 v0 = *(const uint4*)(xy + m0.x * 256 + cl * 8);
        uint4 v1 = *(const uint4*)(xy + m1.x * 256 + cl * 8);
        uint4 v2 = *(const uint4*)(xy + m2.x * 256 + cl * 8);
        uint4 v3 = *(const uint4*)(xy + m3.x * 256 + cl * 8);
        float c0 = __int_as_float(m0.y), c1 = __int_as_float(m1.y);
        float c2 = __int_as_float(m2.y), c3 = __int_as_float(m3.y);
        ACC8(v0, c0) ACC8(v1, c1) ACC8(v2, c2) ACC8(v3, c3)
    }
    for (; j < jend; j += 2) {
        int idx = j + half;
        if (idx < jend) {
            int2 m = nme[idx];
            uint4 v = *(const uint4*)(xy + m.x * 256 + cl * 8);
            float cf = __int_as_float(m.y);
            ACC8(v, cf)
        }
    }

    aY0 += __shfl_xor(aY0, 32, 64); aY1 += __shfl_xor(aY1, 32, 64);
    aX0 += __shfl_xor(aX0, 32, 64); aX1 += __shfl_xor(aX1, 32, 64);
    aY2 += __shfl_xor(aY2, 32, 64); aY3 += __shfl_xor(aY3, 32, 64);
    aX2 += __shfl_xor(aX2, 32, 64); aX3 += __shfl_xor(aX3, 32, 64);
    if (half == 0) {
        float* zr = zp + (((p << 11) + i) << 8) + cl * 8;
        *(float4*)(zr) = make_float4(aY0, aY1, aX0, aX1);
        *(float4*)(zr + 4) = make_float4(aY2, aY3, aX2, aX3);
    }
}

// ---------------- reduce partials + fused output matvecs ----------------
__global__ __launch_bounds__(256) void k_reduce(const float* __restrict__ zp,
                                                const float* __restrict__ W2, const float* __restrict__ b2,
                                                const float* __restrict__ W3, const float* __restrict__ b3,
                                                float* __restrict__ out) {
    int i = blockIdx.x;   // node 0..2046
    int t = threadIdx.x;
    __shared__ float zm[128], zxm[128];
    float s = 0.f;
    #pragma unroll
    for (int p = 0; p < 8; ++p) s += zp[(((p << 11) + i) << 8) + t];
    s *= (1.0f / 64.0f);
    int k = t >> 2, r = t & 3;
    if (r < 2) zm[2 * k + r] = s; else zxm[2 * k + (r - 2)] = s;
    __syncthreads();
    int cc = t & 127;
    if (t < 128) {
        float acc = b2[cc];
        #pragma unroll 8
        for (int f = 0; f < 128; ++f) acc += zm[f] * W2[f * 128 + cc];
        out[i * 128 + cc] = acc;
    } else {
        float acc = b3[cc];
        #pragma unroll 8
        for (int f = 0; f < 128; ++f) acc += (zxm[f] - zm[f]) * W3[f * 128 + cc];
        out[2047 * 128 + i * 128 + cc] = acc;
    }
}

// ---------------- launch ----------------

extern "C" void kernel_launch(void* const* d_in, const int* in_sizes, int n_in,
                              void* d_out, int out_size, void* d_ws, size_t ws_size,
                              hipStream_t stream) {
    const float* x    = (const float*)d_in[0];
    const int* ei     = (const int*)d_in[1];
    const int* center = (const int*)d_in[3];
    const float* W1 = (const float*)d_in[4];
    const float* b1 = (const float*)d_in[5];
    const float* W2 = (const float*)d_in[6];
    const float* b2 = (const float*)d_in[7];
    const float* W3 = (const float*)d_in[8];
    const float* b3 = (const float*)d_in[9];
    const float* Wm = (const float*)d_in[10];
    const float* bm = (const float*)d_in[11];
    float* out = (float*)d_out;

    char* ws = (char*)d_ws;
    int*   degc   = (int*)(ws + 0);            // 512 KB
    float* dis    = (float*)(ws + 524288);     // 512 KB
    float* invdeg = (float*)(ws + 1048576);    // 512 KB
    int*   pos_pn = (int*)(ws + 1572864);      // 65568 B (reserve 66560)
    int*   gstart = (int*)(ws + 1639424);      // 512 KB
    float* A      = (float*)(ws + 2163712);    // 32 KB
    u16*   Wtp    = (u16*)(ws + 2196480);      // 32 KB
    int2*  nme    = (int2*)(ws + 2229248);     // 8 MB
    float* zp     = (float*)(ws + 10617856);   // 16.8 MB
    u16*   xy     = (u16*)(ws + 27395072);     // 67 MB  (total ~94.5 MB)

    k_hist<<<dim3(Gg), dim3(1024), 0, stream>>>(ei, degc, dis, invdeg);
    k_scan_p<<<dim3(8), dim3(1024), 0, stream>>>(degc, pos_pn);
    k_start<<<dim3(Nn / 256), dim3(256), 0, stream>>>(degc, pos_pn, gstart);
    k_scatter<<<dim3(Gg), dim3(1024), 0, stream>>>(ei, dis, gstart, nme);
    k_trans<<<dim3(64), dim3(256), 0, stream>>>(Wm, Wtp);
    k_A<<<dim3(Gg), dim3(128), 0, stream>>>(x, center, invdeg, gstart, degc, nme, W1, b1, Wm, bm, A);
    k_masky<<<dim3(2048), dim3(256), 0, stream>>>(x, Wtp, A, xy);
    k_propx<<<dim3(4096), dim3(256), 0, stream>>>(xy, invdeg, pos_pn, nme, zp);
    k_reduce<<<dim3(Nn - 1), dim3(256), 0, stream>>>(zp, W2, b2, W3, b3, out);
}

// Round 4
// 273.566 us; speedup vs baseline: 1.0189x; 1.0189x over previous
//
#include <hip/hip_runtime.h>

typedef unsigned short u16;
typedef unsigned int uint32;
typedef __bf16 bf16x8 __attribute__((ext_vector_type(8)));
typedef float f32x4 __attribute__((ext_vector_type(4)));

static constexpr int Gg = 64;
static constexpr int Nn = 2048;
static constexpr int Ee = 16384;
static constexpr int GN = Gg * Nn;   // 131072
static constexpr int GE = Gg * Ee;   // 1048576

__device__ __forceinline__ u16 f2u(float f) {  // round-to-nearest-even bf16
    uint32 i = __float_as_uint(f);
    uint32 r = (i + 0x7FFFu + ((i >> 16) & 1u)) >> 16;
    return (u16)r;
}
__device__ __forceinline__ float lo16f(uint32 v) { return __uint_as_float(v << 16); }
__device__ __forceinline__ float hi16f(uint32 v) { return __uint_as_float(v & 0xffff0000u); }

// ---------------- setup kernels ----------------

// per-graph LDS histogram of dst -> degc, dis, invdeg (no global atomics)
__global__ __launch_bounds__(1024) void k_hist(const int* __restrict__ ei, int* __restrict__ deg,
                                               float* __restrict__ dis, float* __restrict__ invdeg) {
    int g = blockIdx.x, t = threadIdx.x;
    __shared__ int h[2048];
    h[t] = 0; h[t + 1024] = 0;
    __syncthreads();
    #pragma unroll
    for (int k = 0; k < 16; ++k) {
        int d = ei[GE + g * Ee + k * 1024 + t];
        atomicAdd(&h[d & (Nn - 1)], 1);
    }
    __syncthreads();
    #pragma unroll
    for (int k = 0; k < 2; ++k) {
        int i = k * 1024 + t;
        int c = h[i];
        deg[(g << 11) + i] = c;
        float dd = 1.0f + (float)c;
        dis[(g << 11) + i] = rsqrtf(dd);
        invdeg[(g << 11) + i] = 1.0f / dd;
    }
}

// per-group (8 graphs) exclusive scan over nodes -> pos_pn[p][i] (absolute, base p<<17)
__global__ void k_scan_p(const int* __restrict__ deg, int* __restrict__ pos_pn) {
    int p = blockIdx.x, t = threadIdx.x;   // 1024 threads, 2 nodes each
    int i0 = 2 * t, i1 = 2 * t + 1;
    int c0 = 0, c1 = 0;
    #pragma unroll
    for (int g8 = 0; g8 < 8; ++g8) {
        int g = p * 8 + g8;
        c0 += deg[(g << 11) + i0];
        c1 += deg[(g << 11) + i1];
    }
    __shared__ int ps[1024];
    ps[t] = c0 + c1; __syncthreads();
    for (int off = 1; off < 1024; off <<= 1) {
        int v = (t >= off) ? ps[t - off] : 0;
        __syncthreads();
        ps[t] += v;
        __syncthreads();
    }
    int base = (p << 17) + ps[t] - (c0 + c1);
    pos_pn[p * 2049 + i0] = base;
    pos_pn[p * 2049 + i1] = base + c0;
    if (t == 1023) pos_pn[p * 2049 + 2048] = (p + 1) << 17;
}

// deterministic per-(g,i) starts within the (p,i) bucket
__global__ void k_start(const int* __restrict__ deg, const int* __restrict__ pos_pn,
                        int* __restrict__ gstart) {
    int i = blockIdx.x * 256 + threadIdx.x;   // node 0..2047
    #pragma unroll
    for (int p = 0; p < 8; ++p) {
        int run = pos_pn[p * 2049 + i];
        #pragma unroll
        for (int g8 = 0; g8 < 8; ++g8) {
            int g = p * 8 + g8;
            gstart[(g << 11) + i] = run;
            run += deg[(g << 11) + i];
        }
    }
}

// per-graph scatter with LDS cursors (no global atomics)
__global__ __launch_bounds__(1024) void k_scatter(const int* __restrict__ ei, const float* __restrict__ dis,
                                                  const int* __restrict__ gstart, int2* __restrict__ nme) {
    int g = blockIdx.x, t = threadIdx.x;
    __shared__ int curs[2048];
    curs[t] = gstart[(g << 11) + t];
    curs[t + 1024] = gstart[(g << 11) + t + 1024];
    __syncthreads();
    #pragma unroll
    for (int k = 0; k < 16; ++k) {
        int e = g * Ee + k * 1024 + t;
        int s = ei[e];          // src gid
        int d = ei[GE + e];     // dst gid
        int p = atomicAdd(&curs[d & (Nn - 1)], 1);
        nme[p] = make_int2(s, __float_as_int(dis[s] * dis[d]));
    }
}

// pack bottom half of Wm into MFMA fragment order (A and B frag layouts are
// symmetric for 16x16x32, so this serves as the A-operand of the transposed GEMM):
// Wtp[((ks*8+ct)*64 + l)*8 + j] = bf16(Wm[(128 + ks*32+lq*8+j)*128 + ct*16+lm]), l=lq*16+lm
__global__ void k_trans(const float* __restrict__ Wm, u16* __restrict__ Wtp) {
    int tid = blockIdx.x * 256 + threadIdx.x;   // 16384
    int j = tid & 7, l = (tid >> 3) & 63, kc = tid >> 9;
    int ks = kc >> 3, ct = kc & 7, lm = l & 15, lq = l >> 4;
    int f = ks * 32 + lq * 8 + j, c = ct * 16 + lm;
    Wtp[tid] = f2u(Wm[(128 + f) * 128 + c]);
}

// A[g] = (ce @ Wm_top) + bm, ce = (x[center]*invdeg + incident edges) @ W1 + b1
__global__ void k_A(const float* __restrict__ x, const int* __restrict__ center,
                    const float* __restrict__ invdeg, const int* __restrict__ gstart,
                    const int* __restrict__ deg, const int2* __restrict__ nme,
                    const float* __restrict__ W1, const float* __restrict__ b1,
                    const float* __restrict__ Wm, const float* __restrict__ bm,
                    float* __restrict__ A) {
    int g = blockIdx.x, t = threadIdx.x;   // 128 threads
    __shared__ float cepre[128], ce[128];
    int cg = (g << 11) + center[g];
    float v = x[cg * 128 + t] * invdeg[cg];
    int p0 = gstart[cg], p1 = p0 + deg[cg];
    for (int e = p0; e < p1; ++e) {          // usually empty (center has no in-edges)
        int2 m = nme[e];
        v += __int_as_float(m.y) * x[m.x * 128 + t];
    }
    cepre[t] = v; __syncthreads();
    float a = b1[t];
    #pragma unroll 8
    for (int f = 0; f < 128; ++f) a += cepre[f] * W1[f * 128 + t];
    ce[t] = a; __syncthreads();
    float o = bm[t];
    #pragma unroll 8
    for (int h = 0; h < 128; ++h) o += ce[h] * Wm[h * 128 + t];
    A[g * 128 + t] = o;
}

// ---------------- mask + y GEMM (MFMA, TRANSPOSED), packed xy ----------------
// xy row (256 u16): group k (u16[4k..4k+4)) = { y[2k], y[2k+1], x[2k], x[2k+1] } bf16
// Computes D = W^T x^T via mfma(A=Wtp-frag, B=x-frag) — same Wtp packing and the
// same x loads as the old orientation (A/B frag layouts are symmetric), but the
// C/D layout (col=lane&15=x-row, row=(lane>>4)*4+reg=channel) now gives each lane
// 4 CONSECUTIVE channels of one x-row = exactly one 16B packed-xy chunk:
//   lane(lm,lq), ct: channels ct*16+lq*4..+4 of row row0+lm ->
//   store {y0,y1,x0,x1,y2,y3,x2,x3} at byte row*512 + ct*64 + lq*16.
// Removes the whole LDS transpose (17408->512B, 655K bank conflicts -> 0) and the
// duplicate xr read window; each 64B line segment completes in ONE store instr
// (keeps round-3's write-efficiency: WRITE was measured at the 67MB ideal).
__global__ __launch_bounds__(256) void k_masky(const float* __restrict__ x,
                                               const u16* __restrict__ Wtp,
                                               const float* __restrict__ A,
                                               u16* __restrict__ xy) {
    __shared__ float sA[128];
    int t = threadIdx.x;
    int tile = blockIdx.x;            // 0..2047, 64 rows each
    int g = tile >> 5;
    if (t < 128) sA[t] = A[g * 128 + t];
    __syncthreads();

    int w = t >> 6, l = t & 63;
    int lm = l & 15, lq = l >> 4;
    int row = tile * 64 + w * 16 + lm;      // this lane's x-row
    const float* xrow = x + row * 128;
    const bf16x8* Ap = (const bf16x8*)Wtp;

    // preload the full k-range of this lane's B fragment (8 x float4)
    float4 xf[8];
    #pragma unroll
    for (int ks = 0; ks < 4; ++ks) {
        xf[2 * ks]     = *(const float4*)(xrow + ks * 32 + lq * 8);
        xf[2 * ks + 1] = *(const float4*)(xrow + ks * 32 + lq * 8 + 4);
    }
    // pack to bf16 B-fragments
    union { u16 u[8]; bf16x8 v; } bf[4];
    #pragma unroll
    for (int ks = 0; ks < 4; ++ks) {
        float4 x0 = xf[2 * ks], x1 = xf[2 * ks + 1];
        bf[ks].u[0] = f2u(x0.x); bf[ks].u[1] = f2u(x0.y);
        bf[ks].u[2] = f2u(x0.z); bf[ks].u[3] = f2u(x0.w);
        bf[ks].u[4] = f2u(x1.x); bf[ks].u[5] = f2u(x1.y);
        bf[ks].u[6] = f2u(x1.z); bf[ks].u[7] = f2u(x1.w);
    }

    f32x4 acc[8] = {};
    #pragma unroll
    for (int ks = 0; ks < 4; ++ks) {
        #pragma unroll
        for (int ct = 0; ct < 8; ++ct) {
            bf16x8 a = Ap[(ks * 8 + ct) * 64 + l];
            acc[ct] = __builtin_amdgcn_mfma_f32_16x16x32_bf16(a, bf[ks].v, acc[ct], 0, 0, 0);
        }
    }

    // epilogue: 4 consecutive channels per (lane, ct) -> one 16B chunk
    u16* orow = xy + row * 256;
    #pragma unroll
    for (int ct = 0; ct < 8; ++ct) {
        int ch = ct * 16 + lq * 4;
        float4 xv = *(const float4*)(xrow + ch);   // L1-hot (row fully loaded above)
        float y0 = fmaxf(acc[ct][0] + sA[ch + 0], 0.f) * xv.x;
        float y1 = fmaxf(acc[ct][1] + sA[ch + 1], 0.f) * xv.y;
        float y2 = fmaxf(acc[ct][2] + sA[ch + 2], 0.f) * xv.z;
        float y3 = fmaxf(acc[ct][3] + sA[ch + 3], 0.f) * xv.w;
        uint4 q;
        q.x = (uint32)f2u(y0)   | ((uint32)f2u(y1)   << 16);
        q.y = (uint32)f2u(xv.x) | ((uint32)f2u(xv.y) << 16);
        q.z = (uint32)f2u(y2)   | ((uint32)f2u(y3)   << 16);
        q.w = (uint32)f2u(xv.z) | ((uint32)f2u(xv.w) << 16);
        *(uint4*)(orow + ct * 32 + lq * 8) = q;
    }
}

// ---------------- propagation: half-wave row mapping, 16 edges in flight ----------------
#define ACC8(v, cf)                                                     \
    aY0 += (cf) * lo16f((v).x); aY1 += (cf) * hi16f((v).x);             \
    aX0 += (cf) * lo16f((v).y); aX1 += (cf) * hi16f((v).y);             \
    aY2 += (cf) * lo16f((v).z); aY3 += (cf) * hi16f((v).z);             \
    aX2 += (cf) * lo16f((v).w); aX3 += (cf) * hi16f((v).w);

__global__ __launch_bounds__(256) void k_propx(const u16* __restrict__ xy,
                                               const float* __restrict__ invdeg,
                                               const int* __restrict__ pos_pn,
                                               const int2* __restrict__ nme,
                                               float* __restrict__ zp) {
    int b = blockIdx.x;
    int p = b & 7, c = b >> 3;
    int t = threadIdx.x, w = t >> 6, l = t & 63;
    int half = l >> 5, cl = l & 31;
    int i = c * 4 + w;
    float aY0 = 0.f, aY1 = 0.f, aY2 = 0.f, aY3 = 0.f;
    float aX0 = 0.f, aX1 = 0.f, aX2 = 0.f, aX3 = 0.f;

    #pragma unroll
    for (int k = 0; k < 4; ++k) {
        int gid = ((p * 8 + 2 * k + half) << 11) + i;
        float cf = invdeg[gid];
        uint4 v = *(const uint4*)(xy + gid * 256 + cl * 8);
        ACC8(v, cf)
    }

    int j = pos_pn[p * 2049 + i], jend = pos_pn[p * 2049 + i + 1];
    // 16 edges per iteration: 8 gather loads in flight per half-wave
    for (; j + 15 < jend; j += 16) {
        int2 m0 = nme[j + half];
        int2 m1 = nme[j + 2 + half];
        int2 m2 = nme[j + 4 + half];
        int2 m3 = nme[j + 6 + half];
        int2 m4 = nme[j + 8 + half];
        int2 m5 = nme[j + 10 + half];
        int2 m6 = nme[j + 12 + half];
        int2 m7 = nme[j + 14 + half];
        uint4 v0 = *(const uint4*)(xy + m0.x * 256 + cl * 8);
        uint4 v1 = *(const uint4*)(xy + m1.x * 256 + cl * 8);
        uint4 v2 = *(const uint4*)(xy + m2.x * 256 + cl * 8);
        uint4 v3 = *(const uint4*)(xy + m3.x * 256 + cl * 8);
        uint4 v4 = *(const uint4*)(xy + m4.x * 256 + cl * 8);
        uint4 v5 = *(const uint4*)(xy + m5.x * 256 + cl * 8);
        uint4 v6 = *(const uint4*)(xy + m6.x * 256 + cl * 8);
        uint4 v7 = *(const uint4*)(xy + m7.x * 256 + cl * 8);
        float c0 = __int_as_float(m0.y), c1 = __int_as_float(m1.y);
        float c2 = __int_as_float(m2.y), c3 = __int_as_float(m3.y);
        float c4 = __int_as_float(m4.y), c5 = __int_as_float(m5.y);
        float c6 = __int_as_float(m6.y), c7 = __int_as_float(m7.y);
        ACC8(v0, c0) ACC8(v1, c1) ACC8(v2, c2) ACC8(v3, c3)
        ACC8(v4, c4) ACC8(v5, c5) ACC8(v6, c6) ACC8(v7, c7)
    }
    for (; j + 7 < jend; j += 8) {
        int2 m0 = nme[j + half];
        int2 m1 = nme[j + 2 + half];
        int2 m2 = nme[j + 4 + half];
        int2 m3 = nme[j + 6 + half];
        uint4 v0 = *(const uint4*)(xy + m0.x * 256 + cl * 8);
        uint4 v1 = *(const uint4*)(xy + m1.x * 256 + cl * 8);
        uint4 v2 = *(const uint4*)(xy + m2.x * 256 + cl * 8);
        uint4 v3 = *(const uint4*)(xy + m3.x * 256 + cl * 8);
        float c0 = __int_as_float(m0.y), c1 = __int_as_float(m1.y);
        float c2 = __int_as_float(m2.y), c3 = __int_as_float(m3.y);
        ACC8(v0, c0) ACC8(v1, c1) ACC8(v2, c2) ACC8(v3, c3)
    }
    for (; j < jend; j += 2) {
        int idx = j + half;
        if (idx < jend) {
            int2 m = nme[idx];
            uint4 v = *(const uint4*)(xy + m.x * 256 + cl * 8);
            float cf = __int_as_float(m.y);
            ACC8(v, cf)
        }
    }

    aY0 += __shfl_xor(aY0, 32, 64); aY1 += __shfl_xor(aY1, 32, 64);
    aX0 += __shfl_xor(aX0, 32, 64); aX1 += __shfl_xor(aX1, 32, 64);
    aY2 += __shfl_xor(aY2, 32, 64); aY3 += __shfl_xor(aY3, 32, 64);
    aX2 += __shfl_xor(aX2, 32, 64); aX3 += __shfl_xor(aX3, 32, 64);
    if (half == 0) {
        float* zr = zp + (((p << 11) + i) << 8) + cl * 8;
        *(float4*)(zr) = make_float4(aY0, aY1, aX0, aX1);
        *(float4*)(zr + 4) = make_float4(aY2, aY3, aX2, aX3);
    }
}

// ---------------- reduce partials + fused output matvecs ----------------
__global__ __launch_bounds__(256) void k_reduce(const float* __restrict__ zp,
                                                const float* __restrict__ W2, const float* __restrict__ b2,
                                                const float* __restrict__ W3, const float* __restrict__ b3,
                                                float* __restrict__ out) {
    int i = blockIdx.x;   // node 0..2046
    int t = threadIdx.x;
    __shared__ float zm[128], zxm[128];
    float s = 0.f;
    #pragma unroll
    for (int p = 0; p < 8; ++p) s += zp[(((p << 11) + i) << 8) + t];
    s *= (1.0f / 64.0f);
    int k = t >> 2, r = t & 3;
    if (r < 2) zm[2 * k + r] = s; else zxm[2 * k + (r - 2)] = s;
    __syncthreads();
    int cc = t & 127;
    if (t < 128) {
        float acc = b2[cc];
        #pragma unroll 8
        for (int f = 0; f < 128; ++f) acc += zm[f] * W2[f * 128 + cc];
        out[i * 128 + cc] = acc;
    } else {
        float acc = b3[cc];
        #pragma unroll 8
        for (int f = 0; f < 128; ++f) acc += (zxm[f] - zm[f]) * W3[f * 128 + cc];
        out[2047 * 128 + i * 128 + cc] = acc;
    }
}

// ---------------- launch ----------------

extern "C" void kernel_launch(void* const* d_in, const int* in_sizes, int n_in,
                              void* d_out, int out_size, void* d_ws, size_t ws_size,
                              hipStream_t stream) {
    const float* x    = (const float*)d_in[0];
    const int* ei     = (const int*)d_in[1];
    const int* center = (const int*)d_in[3];
    const float* W1 = (const float*)d_in[4];
    const float* b1 = (const float*)d_in[5];
    const float* W2 = (const float*)d_in[6];
    const float* b2 = (const float*)d_in[7];
    const float* W3 = (const float*)d_in[8];
    const float* b3 = (const float*)d_in[9];
    const float* Wm = (const float*)d_in[10];
    const float* bm = (const float*)d_in[11];
    float* out = (float*)d_out;

    char* ws = (char*)d_ws;
    int*   degc   = (int*)(ws + 0);            // 512 KB
    float* dis    = (float*)(ws + 524288);     // 512 KB
    float* invdeg = (float*)(ws + 1048576);    // 512 KB
    int*   pos_pn = (int*)(ws + 1572864);      // 65568 B (reserve 66560)
    int*   gstart = (int*)(ws + 1639424);      // 512 KB
    float* A      = (float*)(ws + 2163712);    // 32 KB
    u16*   Wtp    = (u16*)(ws + 2196480);      // 32 KB
    int2*  nme    = (int2*)(ws + 2229248);     // 8 MB
    float* zp     = (float*)(ws + 10617856);   // 16.8 MB
    u16*   xy     = (u16*)(ws + 27395072);     // 67 MB  (total ~94.5 MB)

    k_hist<<<dim3(Gg), dim3(1024), 0, stream>>>(ei, degc, dis, invdeg);
    k_scan_p<<<dim3(8), dim3(1024), 0, stream>>>(degc, pos_pn);
    k_start<<<dim3(Nn / 256), dim3(256), 0, stream>>>(degc, pos_pn, gstart);
    k_scatter<<<dim3(Gg), dim3(1024), 0, stream>>>(ei, dis, gstart, nme);
    k_trans<<<dim3(64), dim3(256), 0, stream>>>(Wm, Wtp);
    k_A<<<dim3(Gg), dim3(128), 0, stream>>>(x, center, invdeg, gstart, degc, nme, W1, b1, Wm, bm, A);
    k_masky<<<dim3(2048), dim3(256), 0, stream>>>(x, Wtp, A, xy);
    k_propx<<<dim3(4096), dim3(256), 0, stream>>>(xy, invdeg, pos_pn, nme, zp);
    k_reduce<<<dim3(Nn - 1), dim3(256), 0, stream>>>(zp, W2, b2, W3, b3, out);
}